// Round 1
// baseline (218.503 us; speedup 1.0000x reference)
//
#include <hip/hip_runtime.h>
#include <hip/hip_bf16.h>

// Problem constants (match reference)
#define B_   8
#define NQ_  64     // N_CANDS
#define CTX_ 512    // CTX_LEN
#define DC_  512    // CONTEXT_SIZE
#define DQ_  512    // QUERY_SIZE
#define H_   256    // HIDDEN
#define EPS_ 1e-5f

// ---------------------------------------------------------------------------
// Kernel 1: out[r][h] = sum_k A[r][k] * W[h][k] (+ bias[h])
// "NT" GEMM: both A and W have K contiguous. Tile 64x64, BK=32, 256 thr, 4x4/thread.
// R and H are multiples of 64, K multiple of 32 for our shapes (no bounds checks).
// ---------------------------------------------------------------------------
__global__ __launch_bounds__(256) void gemm_nt(
    const float* __restrict__ A, const float* __restrict__ W,
    const float* __restrict__ bias, float* __restrict__ out,
    int K, int Hh)
{
    const int BM = 64, BN = 64, BK = 32;
    __shared__ float As[BK][BM + 4];   // row stride 68 floats = 272B (16B-aligned)
    __shared__ float Ws[BK][BN + 4];

    const int row0 = blockIdx.x * BM;
    const int col0 = blockIdx.y * BN;
    const int tid  = threadIdx.x;
    const int tx = tid & 15;          // 16 col groups
    const int ty = tid >> 4;          // 16 row groups

    float acc[4][4] = {};

    for (int k0 = 0; k0 < K; k0 += BK) {
        // Stage A tile (64x32 floats = 512 float4; 2 per thread)
        #pragma unroll
        for (int p = 0; p < 2; ++p) {
            int idx = tid + p * 256;
            int m  = idx >> 3;          // /8 float4-per-row
            int kv = idx & 7;
            float4 v = *(const float4*)&A[(size_t)(row0 + m) * K + k0 + kv * 4];
            As[kv*4+0][m] = v.x; As[kv*4+1][m] = v.y;
            As[kv*4+2][m] = v.z; As[kv*4+3][m] = v.w;
        }
        // Stage W tile (64x32)
        #pragma unroll
        for (int p = 0; p < 2; ++p) {
            int idx = tid + p * 256;
            int n  = idx >> 3;
            int kv = idx & 7;
            float4 v = *(const float4*)&W[(size_t)(col0 + n) * K + k0 + kv * 4];
            Ws[kv*4+0][n] = v.x; Ws[kv*4+1][n] = v.y;
            Ws[kv*4+2][n] = v.z; Ws[kv*4+3][n] = v.w;
        }
        __syncthreads();

        #pragma unroll
        for (int k = 0; k < BK; ++k) {
            float4 a = *(const float4*)&As[k][ty * 4];
            float4 b = *(const float4*)&Ws[k][tx * 4];
            float av[4] = {a.x, a.y, a.z, a.w};
            float bv[4] = {b.x, b.y, b.z, b.w};
            #pragma unroll
            for (int i = 0; i < 4; ++i)
                #pragma unroll
                for (int j = 0; j < 4; ++j)
                    acc[i][j] += av[i] * bv[j];
        }
        __syncthreads();
    }

    // Epilogue: float4 stores per row
    float4 bv4 = make_float4(0.f, 0.f, 0.f, 0.f);
    if (bias) bv4 = *(const float4*)&bias[col0 + tx * 4];
    #pragma unroll
    for (int i = 0; i < 4; ++i) {
        int r = row0 + ty * 4 + i;
        float4 o;
        o.x = acc[i][0] + bv4.x; o.y = acc[i][1] + bv4.y;
        o.z = acc[i][2] + bv4.z; o.w = acc[i][3] + bv4.w;
        *(float4*)&out[(size_t)r * Hh + col0 + tx * 4] = o;
    }
}

// fast tanh: 1 - 2/(exp(2x)+1); saturates correctly for |x| large
__device__ __forceinline__ float tanh_fast(float x) {
    float e = __expf(2.f * x);
    float r = __builtin_amdgcn_rcpf(e + 1.f);
    return 1.f - 2.f * r;
}

// ---------------------------------------------------------------------------
// Kernel 2: one block per (b,q).
//  Phase A: logits[c] = b_o + sum_h W_o[h]*tanh(res_c[b,c,h]+res_q[b,q,h])
//  Phase B: softmax (reference-exact: no max-sub, denom = sum + EPS, mask*exp)
//  Phase C: out[b,q,d] = sum_c w[c]*context[b,c,d]
// ---------------------------------------------------------------------------
__global__ __launch_bounds__(256) void attn_fused(
    const float* __restrict__ res_c,   // B*CTX*H
    const float* __restrict__ res_q,   // B*NQ*H
    const float* __restrict__ context, // B*CTX*DC
    const float* __restrict__ mask,    // B*CTX
    const float* __restrict__ W_o,     // H
    const float* __restrict__ b_o_p,   // scalar
    float* __restrict__ out,           // B*NQ*DC
    float* __restrict__ wout)          // B*NQ*CTX
{
    __shared__ float rqs[H_];
    __shared__ float wos[H_];
    __shared__ float lg[CTX_];
    __shared__ float red[4];

    const int bq = blockIdx.x;
    const int b  = bq >> 6;           // / NQ_
    const int tid = threadIdx.x;
    const int wave = tid >> 6;
    const int lane = tid & 63;

    rqs[tid] = res_q[(size_t)bq * H_ + tid];   // blockDim == H_ == 256
    wos[tid] = W_o[tid];
    __syncthreads();

    const float bo = *b_o_p;
    const float* rc_b = res_c + (size_t)b * CTX_ * H_;

    // Phase A: each wave handles c = wave, wave+4, ...
    const float4 qv = *(const float4*)&rqs[lane * 4];
    const float4 wv = *(const float4*)&wos[lane * 4];
    for (int c = wave; c < CTX_; c += 4) {
        float4 xv = *(const float4*)&rc_b[(size_t)c * H_ + lane * 4];
        float s = wv.x * tanh_fast(xv.x + qv.x)
                + wv.y * tanh_fast(xv.y + qv.y)
                + wv.z * tanh_fast(xv.z + qv.z)
                + wv.w * tanh_fast(xv.w + qv.w);
        #pragma unroll
        for (int off = 32; off; off >>= 1) s += __shfl_down(s, off);
        if (lane == 0) lg[c] = s + bo;
    }
    __syncthreads();

    // Phase B: softmax, reference-exact ordering
    float we[2];
    float local = 0.f;
    #pragma unroll
    for (int u = 0; u < 2; ++u) {
        int c = tid + u * 256;
        float e = mask[b * CTX_ + c] * __expf(lg[c]);
        we[u] = e;
        local += e;
    }
    #pragma unroll
    for (int off = 32; off; off >>= 1) local += __shfl_down(local, off);
    if (lane == 0) red[wave] = local;
    __syncthreads();
    const float denom = red[0] + red[1] + red[2] + red[3] + EPS_;
    const float inv = 1.f / denom;
    #pragma unroll
    for (int u = 0; u < 2; ++u) {
        int c = tid + u * 256;
        float w = we[u] * inv;
        lg[c] = w;
        wout[(size_t)bq * CTX_ + c] = w;
    }
    __syncthreads();

    // Phase C: weighted context sum; thread owns d = tid*2, tid*2+1
    const float* ctx_b = context + (size_t)b * CTX_ * DC_;
    const int d = tid * 2;
    float ax = 0.f, ay = 0.f;
    #pragma unroll 8
    for (int c = 0; c < CTX_; ++c) {
        float w = lg[c];
        float2 v = *(const float2*)&ctx_b[(size_t)c * DC_ + d];
        ax += w * v.x;
        ay += w * v.y;
    }
    *(float2*)&out[(size_t)bq * DC_ + d] = make_float2(ax, ay);
}

extern "C" void kernel_launch(void* const* d_in, const int* in_sizes, int n_in,
                              void* d_out, int out_size, void* d_ws, size_t ws_size,
                              hipStream_t stream) {
    const float* query   = (const float*)d_in[0];  // B,NQ,DQ
    const float* context = (const float*)d_in[1];  // B,CTX,DC
    const float* mask    = (const float*)d_in[2];  // B,CTX
    const float* W_c     = (const float*)d_in[3];  // H,DC
    const float* b_c     = (const float*)d_in[4];  // H
    const float* W_q     = (const float*)d_in[5];  // H,DQ
    const float* W_o     = (const float*)d_in[6];  // H
    const float* b_o     = (const float*)d_in[7];  // scalar

    float* out  = (float*)d_out;                   // B,NQ,DC
    float* wout = out + (size_t)B_ * NQ_ * DC_;    // B,NQ,CTX

    float* res_c = (float*)d_ws;                       // B*CTX*H = 1M floats (4MB)
    float* res_q = res_c + (size_t)B_ * CTX_ * H_;     // B*NQ*H = 128K floats

    // res_c = context . W_c^T + b_c   (4096 x 256, K=512)
    gemm_nt<<<dim3((B_ * CTX_) / 64, H_ / 64), 256, 0, stream>>>(
        context, W_c, b_c, res_c, DC_, H_);
    // res_q = query . W_q^T           (512 x 256, K=512)
    gemm_nt<<<dim3((B_ * NQ_) / 64, H_ / 64), 256, 0, stream>>>(
        query, W_q, nullptr, res_q, DQ_, H_);
    // fused scoring + softmax + weighted sum
    attn_fused<<<B_ * NQ_, 256, 0, stream>>>(
        res_c, res_q, context, mask, W_o, b_o, out, wout);
}

// Round 2
// 149.879 us; speedup vs baseline: 1.4579x; 1.4579x over previous
//
#include <hip/hip_runtime.h>
#include <hip/hip_bf16.h>

// Problem constants (match reference)
#define B_   8
#define NQ_  64     // N_CANDS
#define CTX_ 512    // CTX_LEN
#define DC_  512    // CONTEXT_SIZE
#define DQ_  512    // QUERY_SIZE
#define H_   256    // HIDDEN
#define EPS_ 1e-5f

// ---------------------------------------------------------------------------
// Kernel 1: BOTH input GEMMs in one dispatch.
// out[r][h] = sum_k A[r][k] * W[h][k] (+ bias[h]); K=512, H=256.
// rows = 4096 (context->res_c, blocks rt<64) ++ 512 (query->res_q, rt>=64).
// Tile 64x64, BK=32, 512 threads, 8 outputs/thread (2 rows x 4 cols).
// ---------------------------------------------------------------------------
__global__ __launch_bounds__(512) void gemm_both(
    const float* __restrict__ ctx, const float* __restrict__ query,
    const float* __restrict__ W_c, const float* __restrict__ b_c,
    const float* __restrict__ W_q,
    float* __restrict__ res_c, float* __restrict__ res_q)
{
    __shared__ float As[32][68];   // k-major; 68-float stride (272B, 16B-aligned)
    __shared__ float Ws[32][68];

    const int rt = blockIdx.x;     // 0..71 row tiles
    const int ct = blockIdx.y;     // 0..3 col tiles (H/64)

    const float* A; const float* W; const float* bias; float* out; int row0;
    if (rt < 64) { A = ctx;   W = W_c; bias = b_c;     out = res_c; row0 = rt * 64; }
    else         { A = query; W = W_q; bias = nullptr; out = res_q; row0 = (rt - 64) * 64; }

    const int t  = threadIdx.x;
    const int tm = t >> 3;         // 0..63: tile row for staging
    const int tk = t & 7;          // 0..7:  float4 index within 32-k row
    const int tx = t & 15;         // 16 col groups of 4
    const int ty = t >> 4;         // 32 row groups of 2

    const int col0 = ct * 64;
    float acc[2][4] = {};

    for (int k0 = 0; k0 < 512; k0 += 32) {
        float4 av = *(const float4*)&A[(size_t)(row0 + tm) * 512 + k0 + tk * 4];
        float4 wv = *(const float4*)&W[(size_t)(col0 + tm) * 512 + k0 + tk * 4];
        __syncthreads();           // prior tile's compute done before overwrite
        As[tk*4+0][tm] = av.x; As[tk*4+1][tm] = av.y;
        As[tk*4+2][tm] = av.z; As[tk*4+3][tm] = av.w;
        Ws[tk*4+0][tm] = wv.x; Ws[tk*4+1][tm] = wv.y;
        Ws[tk*4+2][tm] = wv.z; Ws[tk*4+3][tm] = wv.w;
        __syncthreads();

        #pragma unroll
        for (int k = 0; k < 32; ++k) {
            float2 a = *(const float2*)&As[k][ty * 2];
            float4 b = *(const float4*)&Ws[k][tx * 4];
            acc[0][0] += a.x * b.x; acc[0][1] += a.x * b.y;
            acc[0][2] += a.x * b.z; acc[0][3] += a.x * b.w;
            acc[1][0] += a.y * b.x; acc[1][1] += a.y * b.y;
            acc[1][2] += a.y * b.z; acc[1][3] += a.y * b.w;
        }
    }

    float4 bv = make_float4(0.f, 0.f, 0.f, 0.f);
    if (bias) bv = *(const float4*)&bias[col0 + tx * 4];
    #pragma unroll
    for (int i = 0; i < 2; ++i) {
        int r = row0 + ty * 2 + i;
        float4 o;
        o.x = acc[i][0] + bv.x; o.y = acc[i][1] + bv.y;
        o.z = acc[i][2] + bv.z; o.w = acc[i][3] + bv.w;
        *(float4*)&out[(size_t)r * H_ + col0 + tx * 4] = o;
    }
}

// fast tanh: 1 - 2/(exp(2x)+1); saturates correctly for |x| large
__device__ __forceinline__ float tanh_fast(float x) {
    float e = __expf(2.f * x);
    float r = __builtin_amdgcn_rcpf(e + 1.f);
    return 1.f - 2.f * r;
}

// ---------------------------------------------------------------------------
// Kernel 2: one 512-thread block per (b,q). XCD-swizzled: b = blockIdx&7 so
// each XCD's L2 holds exactly one batch's context (1MB) + res_c (512KB).
//  Phase A: logits via 16-lane-group dot products (4 shfl per 4 logits)
//  Phase B: softmax (reference-exact: no max-sub, denom = sum + EPS)
//  Phase C: out[d] = sum_c w[c]*context[b,c,d], c-range split 4 ways
// ---------------------------------------------------------------------------
__global__ __launch_bounds__(512) void attn_fused(
    const float* __restrict__ res_c,   // B*CTX*H
    const float* __restrict__ res_q,   // B*NQ*H
    const float* __restrict__ context, // B*CTX*DC
    const float* __restrict__ mask,    // B*CTX
    const float* __restrict__ W_o,     // H
    const float* __restrict__ b_o_p,   // scalar
    float* __restrict__ out,           // B*NQ*DC
    float* __restrict__ wout)          // B*NQ*CTX
{
    __shared__ float rqs[H_];
    __shared__ float wos[H_];
    __shared__ float lg[CTX_];
    __shared__ float red[8];
    __shared__ float4 pc[3][128];

    // XCD swizzle: consecutive blockIdx round-robin over 8 XCDs -> put all 64
    // q-blocks of batch b on XCD b.
    const int b  = blockIdx.x & 7;
    const int q  = blockIdx.x >> 3;
    const int bq = b * NQ_ + q;

    const int tid  = threadIdx.x;
    const int wave = tid >> 6;
    const int lane = tid & 63;

    if (tid < H_) {
        rqs[tid] = res_q[(size_t)bq * H_ + tid];
        wos[tid] = W_o[tid];
    }
    __syncthreads();

    const float bo = *b_o_p;
    const float* rc_b = res_c + (size_t)b * CTX_ * H_;

    // Phase A: wave w owns c in [w*64, w*64+64), 16 iters x 4 c.
    // lane bits 0-3 (cq) select the h-chunk: h = cq*4 + 64*k, k=0..3.
    const int cq = lane & 15;
    float4 rq[4], wo[4];
    #pragma unroll
    for (int k = 0; k < 4; ++k) {
        rq[k] = ((const float4*)rqs)[cq + 16 * k];
        wo[k] = ((const float4*)wos)[cq + 16 * k];
    }
    const int cbase = wave * 64;
    for (int it = 0; it < 16; ++it) {
        int c = cbase + it * 4 + (lane >> 4);
        const float* p = rc_b + (size_t)c * H_ + cq * 4;
        float4 x0 = *(const float4*)(p);
        float4 x1 = *(const float4*)(p + 64);
        float4 x2 = *(const float4*)(p + 128);
        float4 x3 = *(const float4*)(p + 192);
        float s;
        s  = wo[0].x * tanh_fast(x0.x + rq[0].x);
        s += wo[0].y * tanh_fast(x0.y + rq[0].y);
        s += wo[0].z * tanh_fast(x0.z + rq[0].z);
        s += wo[0].w * tanh_fast(x0.w + rq[0].w);
        s += wo[1].x * tanh_fast(x1.x + rq[1].x);
        s += wo[1].y * tanh_fast(x1.y + rq[1].y);
        s += wo[1].z * tanh_fast(x1.z + rq[1].z);
        s += wo[1].w * tanh_fast(x1.w + rq[1].w);
        s += wo[2].x * tanh_fast(x2.x + rq[2].x);
        s += wo[2].y * tanh_fast(x2.y + rq[2].y);
        s += wo[2].z * tanh_fast(x2.z + rq[2].z);
        s += wo[2].w * tanh_fast(x2.w + rq[2].w);
        s += wo[3].x * tanh_fast(x3.x + rq[3].x);
        s += wo[3].y * tanh_fast(x3.y + rq[3].y);
        s += wo[3].z * tanh_fast(x3.z + rq[3].z);
        s += wo[3].w * tanh_fast(x3.w + rq[3].w);
        // reduce across the 16 lanes of the c-group (lane bits 0-3)
        s += __shfl_xor(s, 1);
        s += __shfl_xor(s, 2);
        s += __shfl_xor(s, 4);
        s += __shfl_xor(s, 8);
        if (cq == 0) lg[c] = s + bo;
    }
    __syncthreads();

    // Phase B: softmax, reference-exact ordering. Thread t owns c = t.
    float e = mask[b * CTX_ + tid] * __expf(lg[tid]);
    float loc = e;
    #pragma unroll
    for (int off = 32; off; off >>= 1) loc += __shfl_down(loc, off);
    if (lane == 0) red[wave] = loc;
    __syncthreads();
    float denom = red[0] + red[1] + red[2] + red[3]
                + red[4] + red[5] + red[6] + red[7] + EPS_;
    float w = e * (1.f / denom);
    lg[tid] = w;
    wout[(size_t)bq * CTX_ + tid] = w;
    __syncthreads();

    // Phase C: quarter = tid>>7 owns c in [quarter*128, +128); dt = tid&127
    // owns d = dt*4 (float4). Combine 4 partials via LDS.
    const int quarter = tid >> 7;
    const int dt = tid & 127;
    const float* cb = context + (size_t)b * CTX_ * DC_;
    float4 acc = make_float4(0.f, 0.f, 0.f, 0.f);
    const int c0 = quarter * 128;
    #pragma unroll 4
    for (int c = c0; c < c0 + 128; ++c) {
        float wv = lg[c];
        float4 v = *(const float4*)&cb[(size_t)c * DC_ + dt * 4];
        acc.x += wv * v.x; acc.y += wv * v.y;
        acc.z += wv * v.z; acc.w += wv * v.w;
    }
    if (quarter) pc[quarter - 1][dt] = acc;
    __syncthreads();
    if (quarter == 0) {
        float4 p0 = pc[0][dt], p1 = pc[1][dt], p2 = pc[2][dt];
        acc.x += p0.x + p1.x + p2.x;
        acc.y += p0.y + p1.y + p2.y;
        acc.z += p0.z + p1.z + p2.z;
        acc.w += p0.w + p1.w + p2.w;
        *(float4*)&out[(size_t)bq * DC_ + dt * 4] = acc;
    }
}

extern "C" void kernel_launch(void* const* d_in, const int* in_sizes, int n_in,
                              void* d_out, int out_size, void* d_ws, size_t ws_size,
                              hipStream_t stream) {
    const float* query   = (const float*)d_in[0];  // B,NQ,DQ
    const float* context = (const float*)d_in[1];  // B,CTX,DC
    const float* mask    = (const float*)d_in[2];  // B,CTX
    const float* W_c     = (const float*)d_in[3];  // H,DC
    const float* b_c     = (const float*)d_in[4];  // H
    const float* W_q     = (const float*)d_in[5];  // H,DQ
    const float* W_o     = (const float*)d_in[6];  // H
    const float* b_o     = (const float*)d_in[7];  // scalar

    float* out  = (float*)d_out;                   // B,NQ,DC
    float* wout = out + (size_t)B_ * NQ_ * DC_;    // B,NQ,CTX

    float* res_c = (float*)d_ws;                       // B*CTX*H floats (4MB)
    float* res_q = res_c + (size_t)B_ * CTX_ * H_;     // B*NQ*H floats

    // both input GEMMs, one dispatch: 72 row-tiles (64 ctx + 8 query) x 4 col-tiles
    gemm_both<<<dim3(72, 4), 512, 0, stream>>>(
        context, query, W_c, b_c, W_q, res_c, res_q);
    // fused scoring + softmax + weighted sum
    attn_fused<<<B_ * NQ_, 512, 0, stream>>>(
        res_c, res_q, context, mask, W_o, b_o, out, wout);
}